// Round 1
// baseline (396.065 us; speedup 1.0000x reference)
//
#include <hip/hip_runtime.h>

// Problem: b=8, c=192, h=w=128 -> n=16384.
// Algebraic reduction: out[b] = M[b] @ X[b] + bias2, where
//   G[b]  = X[b] @ X[b]^T                      (192x192 Gram, X = x_in[b] as [192,16384])
//   Wq'=w_q@w_split, Wk'=w_k@w_split, Wv'=w_v@w_split, Wo2=w_out@w_proj, bias2=w_out@b_proj
//   L_raw = Wk' G Wq'^T ; qn=sqrt(diag(Wq' G Wq'^T)) ; kn=sqrt(diag(Wk' G Wk'^T))
//   A[b]  = softmax_rows(L_raw / (kn outer qn))
//   M[b]  = Wo2 @ A[b] @ Wv'
// Heavy phases (Gram, final GEMM) use bf16 MFMA 16x16x32 with fp32 accum.

static constexpr int B_ = 8;
static constexpr int C_ = 192;
static constexpr int N_ = 16384;

using u16x8 = __attribute__((ext_vector_type(8))) unsigned short;
using bf16x8 = __attribute__((ext_vector_type(8))) __bf16;
using f32x4 = __attribute__((ext_vector_type(4))) float;

__device__ __forceinline__ unsigned short f2bf(float f) {
  unsigned int u = __builtin_bit_cast(unsigned int, f);
  u += 0x7FFFu + ((u >> 16) & 1u);   // RNE
  return (unsigned short)(u >> 16);
}

__device__ __forceinline__ f32x4 mfma16(u16x8 a, u16x8 b, f32x4 c) {
  return __builtin_amdgcn_mfma_f32_16x16x32_bf16(
      __builtin_bit_cast(bf16x8, a), __builtin_bit_cast(bf16x8, b), c, 0, 0, 0);
}

// ---------------- fold weights: Wq',Wk',Wv',Wo2,bias2 ----------------
__global__ void fold_kernel(const float* __restrict__ wsplit, const float* __restrict__ wq,
                            const float* __restrict__ wk, const float* __restrict__ wv,
                            const float* __restrict__ wproj, const float* __restrict__ bproj,
                            const float* __restrict__ wout,
                            float* __restrict__ Wq, float* __restrict__ Wk,
                            float* __restrict__ Wv, float* __restrict__ Wo2,
                            float* __restrict__ bias2) {
  int idx = blockIdx.x * 256 + threadIdx.x;
  if (idx < C_) {
    float s = 0.f;
    for (int c = 0; c < C_; ++c) s += wout[idx * C_ + c] * bproj[c];
    bias2[idx] = s;
  }
  if (idx >= 4 * C_ * C_) return;
  int which = idx / (C_ * C_);
  int rem = idx % (C_ * C_);
  int o = rem / C_, c = rem % C_;
  const float* A = (which == 0) ? wq : (which == 1) ? wk : (which == 2) ? wv : wout;
  const float* Bm = (which == 3) ? wproj : wsplit;
  float s = 0.f;
  for (int e = 0; e < C_; ++e) s += A[o * C_ + e] * Bm[e * C_ + c];
  float* dst = (which == 0) ? Wq : (which == 1) ? Wk : (which == 2) ? Wv : Wo2;
  dst[rem] = s;
}

// ---------------- Gram: G[b] = X X^T via bf16 MFMA, atomic fp32 reduce ----------------
// grid (32 k-chunks, 8 batches), 384 threads (6 waves). Wave w owns G rows [32w,32w+32).
__global__ __launch_bounds__(384) void gram_kernel(const float* __restrict__ xin,
                                                   float* __restrict__ G) {
  const int b = blockIdx.y;
  const int k0 = blockIdx.x * 512;                 // KC = 512
  __shared__ unsigned short Xs[C_][72];            // 64 k cols, pitch 72 (pad: 2-way conflicts only)
  const int tid = threadIdx.x;
  const int wv = tid >> 6;
  const int lane = tid & 63;
  const int ln = lane & 15, mq = lane >> 4;
  const float* xb = xin + (size_t)b * C_ * N_;

  f32x4 acc[2][12];
#pragma unroll
  for (int i = 0; i < 2; ++i)
#pragma unroll
    for (int j = 0; j < 12; ++j) acc[i][j] = (f32x4)0.0f;

  for (int s = 0; s < 8; ++s) {                    // 8 sub-stages of 64 k
    const int kbase = k0 + s * 64;
    // stage 192x64 fp32 -> bf16 LDS (coalesced float4 reads)
#pragma unroll
    for (int j = 0; j < 8; ++j) {
      int lin = j * 384 + tid;                     // 0..3071 over (c, k4)
      int c = lin >> 4, k4 = lin & 15;
      float4 v = *(const float4*)(xb + (size_t)c * N_ + kbase + k4 * 4);
      int k = k4 * 4;
      Xs[c][k] = f2bf(v.x); Xs[c][k + 1] = f2bf(v.y);
      Xs[c][k + 2] = f2bf(v.z); Xs[c][k + 3] = f2bf(v.w);
    }
    __syncthreads();
#pragma unroll
    for (int ks = 0; ks < 2; ++ks) {               // two K=32 MFMA steps
      const int kk = ks * 32 + mq * 8;
      u16x8 a0 = *(const u16x8*)&Xs[32 * wv + ln][kk];
      u16x8 a1 = *(const u16x8*)&Xs[32 * wv + 16 + ln][kk];
#pragma unroll
      for (int ct = 0; ct < 12; ++ct) {
        u16x8 bf = *(const u16x8*)&Xs[ct * 16 + ln][kk];
        acc[0][ct] = mfma16(a0, bf, acc[0][ct]);
        acc[1][ct] = mfma16(a1, bf, acc[1][ct]);
      }
    }
    __syncthreads();
  }
  float* Gb = G + (size_t)b * C_ * C_;
#pragma unroll
  for (int i = 0; i < 2; ++i)
#pragma unroll
    for (int ct = 0; ct < 12; ++ct)
#pragma unroll
      for (int r = 0; r < 4; ++r) {
        int row = 32 * wv + 16 * i + mq * 4 + r;   // D row from A's m
        int col = ct * 16 + ln;                    // D col from B's n
        atomicAdd(&Gb[row * C_ + col], acc[i][ct][r]);
      }
}

// ---------------- middle (all fp32, tiny) ----------------
__global__ void tqk_kernel(const float* __restrict__ Wq, const float* __restrict__ Wk,
                           const float* __restrict__ G, float* __restrict__ Tq,
                           float* __restrict__ Tk) {
  int idx = blockIdx.x * 256 + threadIdx.x;        // 2*B*C*C
  if (idx >= 2 * B_ * C_ * C_) return;
  int which = idx / (B_ * C_ * C_);
  int rem = idx % (B_ * C_ * C_);
  int b = rem / (C_ * C_);
  int rc = rem % (C_ * C_);
  int d = rc / C_, cp = rc % C_;
  const float* W = which ? Wk : Wq;
  const float* Gb = G + (size_t)b * C_ * C_;
  float s = 0.f;
  for (int c = 0; c < C_; ++c) s += W[d * C_ + c] * Gb[c * C_ + cp];
  (which ? Tk : Tq)[rem] = s;
}

__global__ void norms_kernel(const float* __restrict__ Tq, const float* __restrict__ Tk,
                             const float* __restrict__ Wq, const float* __restrict__ Wk,
                             float* __restrict__ qn, float* __restrict__ kn) {
  int idx = blockIdx.x * 256 + threadIdx.x;        // 2*B*C
  if (idx >= 2 * B_ * C_) return;
  int which = idx / (B_ * C_);
  int rem = idx % (B_ * C_);
  int b = rem / C_, d = rem % C_;
  const float* T = which ? Tk : Tq;
  const float* W = which ? Wk : Wq;
  float s = 0.f;
  for (int c = 0; c < C_; ++c) s += T[((size_t)b * C_ + d) * C_ + c] * W[d * C_ + c];
  float nv = fmaxf(sqrtf(fmaxf(s, 0.f)), 1e-12f);  // F.normalize eps
  (which ? kn : qn)[rem] = nv;
}

// one block per (b, cc) row: logits + softmax over dd
__global__ __launch_bounds__(192) void attn_kernel(const float* __restrict__ Tk,
                                                   const float* __restrict__ Wq,
                                                   const float* __restrict__ qn,
                                                   const float* __restrict__ kn,
                                                   float* __restrict__ Aout) {
  const int b = blockIdx.y, cc = blockIdx.x, dd = threadIdx.x;
  __shared__ float tkrow[C_];
  __shared__ float red[256];
  tkrow[dd] = Tk[((size_t)b * C_ + cc) * C_ + dd];
  __syncthreads();
  const float* Wrow = Wq + dd * C_;
  float s = 0.f;
  for (int c = 0; c < C_; ++c) s += tkrow[c] * Wrow[c];
  float lg = s / (kn[b * C_ + cc] * qn[b * C_ + dd]);
  red[dd] = lg;
  if (dd < 64) red[192 + dd] = -1e30f;
  __syncthreads();
  for (int st = 128; st > 0; st >>= 1) {
    if (dd < st) red[dd] = fmaxf(red[dd], red[dd + st]);
    __syncthreads();
  }
  float mx = red[0];
  __syncthreads();
  float e = expf(lg - mx);
  red[dd] = e;
  if (dd < 64) red[192 + dd] = 0.f;
  __syncthreads();
  for (int st = 128; st > 0; st >>= 1) {
    if (dd < st) red[dd] += red[dd + st];
    __syncthreads();
  }
  float inv = 1.f / red[0];
  Aout[((size_t)b * C_ + cc) * C_ + dd] = e * inv;
}

__global__ void av_kernel(const float* __restrict__ Aw, const float* __restrict__ Wv,
                          float* __restrict__ Tv) {
  int idx = blockIdx.x * 256 + threadIdx.x;        // B*C*C
  if (idx >= B_ * C_ * C_) return;
  int b = idx / (C_ * C_);
  int rc = idx % (C_ * C_);
  int i = rc / C_, j = rc % C_;
  float s = 0.f;
  for (int c = 0; c < C_; ++c) s += Aw[((size_t)b * C_ + i) * C_ + c] * Wv[c * C_ + j];
  Tv[idx] = s;
}

__global__ void m_kernel(const float* __restrict__ Wo2, const float* __restrict__ Tv,
                         float* __restrict__ Mout) {
  int idx = blockIdx.x * 256 + threadIdx.x;        // B*C*C
  if (idx >= B_ * C_ * C_) return;
  int b = idx / (C_ * C_);
  int rc = idx % (C_ * C_);
  int i = rc / C_, j = rc % C_;
  float s = 0.f;
  for (int c = 0; c < C_; ++c) s += Wo2[i * C_ + c] * Tv[((size_t)b * C_ + c) * C_ + j];
  Mout[idx] = s;
}

// ---------------- final: out[b] = M[b] @ X[b] + bias2, bf16 MFMA ----------------
// grid (128 p-tiles, 8 batches), 384 threads (6 waves). Wave w owns out rows [32w,32w+32).
// X tile transposed into LDS as [p][c] so B-frags (n=p, k=c) are contiguous 16B reads.
__global__ __launch_bounds__(384) void final_kernel(const float* __restrict__ xin,
                                                    const float* __restrict__ Mw,
                                                    const float* __restrict__ bias2,
                                                    float* __restrict__ out) {
  const int b = blockIdx.y;
  const int p0 = blockIdx.x * 128;
  __shared__ unsigned short Ts[128][200];          // pitch 200 (pad: 2-way conflicts only)
  const int tid = threadIdx.x;
  const int wv = tid >> 6;
  const int lane = tid & 63;
  const int ln = lane & 15, mq = lane >> 4;
  const float* Mb = Mw + (size_t)b * C_ * C_;

  // persistent A-frags: M rows for this wave, all 6 K-steps (L2-cached reads)
  u16x8 afr[6][2];
  float bo[2][4];
#pragma unroll
  for (int i = 0; i < 2; ++i) {
    int row = 32 * wv + 16 * i + ln;
#pragma unroll
    for (int kc = 0; kc < 6; ++kc) {
      const float* src = Mb + row * C_ + kc * 32 + mq * 8;
      float4 u0 = *(const float4*)(src);
      float4 u1 = *(const float4*)(src + 4);
      u16x8 a;
      a[0] = f2bf(u0.x); a[1] = f2bf(u0.y); a[2] = f2bf(u0.z); a[3] = f2bf(u0.w);
      a[4] = f2bf(u1.x); a[5] = f2bf(u1.y); a[6] = f2bf(u1.z); a[7] = f2bf(u1.w);
      afr[kc][i] = a;
    }
#pragma unroll
    for (int r = 0; r < 4; ++r) bo[i][r] = bias2[32 * wv + 16 * i + mq * 4 + r];
  }

  // stage X[:, p0:p0+128] transposed -> Ts[p][c] bf16
#pragma unroll
  for (int j = 0; j < 16; ++j) {
    int lin = j * 384 + tid;                       // 0..6143 over (c, p4)
    int c = lin >> 5, p4 = lin & 31;
    float4 v = *(const float4*)(xin + ((size_t)b * C_ + c) * N_ + p0 + p4 * 4);
    Ts[p4 * 4 + 0][c] = f2bf(v.x);
    Ts[p4 * 4 + 1][c] = f2bf(v.y);
    Ts[p4 * 4 + 2][c] = f2bf(v.z);
    Ts[p4 * 4 + 3][c] = f2bf(v.w);
  }
  __syncthreads();

#pragma unroll
  for (int pt = 0; pt < 8; ++pt) {
    f32x4 acc0 = (f32x4)0.0f, acc1 = (f32x4)0.0f;
#pragma unroll
    for (int kc = 0; kc < 6; ++kc) {
      u16x8 bf = *(const u16x8*)&Ts[pt * 16 + ln][kc * 32 + mq * 8];
      acc0 = mfma16(afr[kc][0], bf, acc0);
      acc1 = mfma16(afr[kc][1], bf, acc1);
    }
#pragma unroll
    for (int r = 0; r < 4; ++r) {
      int row0 = 32 * wv + mq * 4 + r;
      int row1 = row0 + 16;
      int p = p0 + pt * 16 + ln;
      out[((size_t)b * C_ + row0) * N_ + p] = acc0[r] + bo[0][r];
      out[((size_t)b * C_ + row1) * N_ + p] = acc1[r] + bo[1][r];
    }
  }
}

extern "C" void kernel_launch(void* const* d_in, const int* in_sizes, int n_in,
                              void* d_out, int out_size, void* d_ws, size_t ws_size,
                              hipStream_t stream) {
  const float* xin    = (const float*)d_in[0];
  const float* wsplit = (const float*)d_in[1];
  const float* wq     = (const float*)d_in[2];
  const float* wk     = (const float*)d_in[3];
  const float* wv     = (const float*)d_in[4];
  const float* wproj  = (const float*)d_in[5];
  const float* bproj  = (const float*)d_in[6];
  const float* wout   = (const float*)d_in[7];
  float* out = (float*)d_out;

  float* ws = (float*)d_ws;
  const int CC2 = C_ * C_;          // 36864
  float* G     = ws;                         // B*CC2
  float* Wq    = G + B_ * CC2;               // CC2
  float* Wk    = Wq + CC2;
  float* Wv    = Wk + CC2;
  float* Wo2   = Wv + CC2;
  float* bias2 = Wo2 + CC2;                  // C_ (pad to 256)
  float* Tq    = bias2 + 256;                // B*CC2
  float* Tk    = Tq + B_ * CC2;
  float* qn    = Tk + B_ * CC2;              // B*C_
  float* kn    = qn + B_ * C_;
  float* Aw    = kn + B_ * C_;               // B*CC2
  float* Tv    = Aw + B_ * CC2;
  float* Mw    = Tv + B_ * CC2;

  hipMemsetAsync(G, 0, (size_t)B_ * CC2 * sizeof(float), stream);
  fold_kernel<<<(4 * CC2 + 255) / 256, 256, 0, stream>>>(wsplit, wq, wk, wv, wproj, bproj,
                                                          wout, Wq, Wk, Wv, Wo2, bias2);
  gram_kernel<<<dim3(32, B_), 384, 0, stream>>>(xin, G);
  tqk_kernel<<<(2 * B_ * CC2 + 255) / 256, 256, 0, stream>>>(Wq, Wk, G, Tq, Tk);
  norms_kernel<<<(2 * B_ * C_ + 255) / 256, 256, 0, stream>>>(Tq, Tk, Wq, Wk, qn, kn);
  attn_kernel<<<dim3(C_, B_), 192, 0, stream>>>(Tk, Wq, qn, kn, Aw);
  av_kernel<<<(B_ * CC2 + 255) / 256, 256, 0, stream>>>(Aw, Wv, Tv);
  m_kernel<<<(B_ * CC2 + 255) / 256, 256, 0, stream>>>(Wo2, Tv, Mw);
  final_kernel<<<dim3(N_ / 128, B_), 384, 0, stream>>>(xin, Mw, bias2, out);
}

// Round 2
// 334.704 us; speedup vs baseline: 1.1833x; 1.1833x over previous
//
#include <hip/hip_runtime.h>

// out[b] = M[b] @ X[b] + bias2, where (X = x_in[b] as [192,16384])
//   G[b]  = X X^T (Gram) ; Wq'=w_q@w_split etc.; Wo2=w_out@w_proj; bias2=w_out@b_proj
//   Tk = Wk' G ; qn[d]=sqrt(Wq'[d] G Wq'[d]^T) ; kn[cc]=sqrt(Tk[cc]·Wk'[cc])
//   A = softmax_rows(Tk Wq'^T / (kn ⊗ qn)) ; M = Wo2 (A Wv')
// Heavy phases (Gram, final GEMM) use bf16 MFMA 16x16x32 with fp32 accum.

static constexpr int B_ = 8;
static constexpr int C_ = 192;
static constexpr int N_ = 16384;
static constexpr int CC2 = C_ * C_;
static constexpr int NCHUNK = 32;

using u16x8 = __attribute__((ext_vector_type(8))) unsigned short;
using bf16x8 = __attribute__((ext_vector_type(8))) __bf16;
using f32x4 = __attribute__((ext_vector_type(4))) float;

__device__ __forceinline__ unsigned short f2bf(float f) {
  unsigned int u = __builtin_bit_cast(unsigned int, f);
  u += 0x7FFFu + ((u >> 16) & 1u);   // RNE
  return (unsigned short)(u >> 16);
}

__device__ __forceinline__ f32x4 mfma16(u16x8 a, u16x8 b, f32x4 c) {
  return __builtin_amdgcn_mfma_f32_16x16x32_bf16(
      __builtin_bit_cast(bf16x8, a), __builtin_bit_cast(bf16x8, b), c, 0, 0, 0);
}

// ---------------- fold weights: Wq',WqT,Wk',Wv',Wo2,bias2 ----------------
__global__ void fold_kernel(const float* __restrict__ wsplit, const float* __restrict__ wq,
                            const float* __restrict__ wk, const float* __restrict__ wv,
                            const float* __restrict__ wproj, const float* __restrict__ bproj,
                            const float* __restrict__ wout,
                            float* __restrict__ Wq, float* __restrict__ WqT,
                            float* __restrict__ Wk, float* __restrict__ Wv,
                            float* __restrict__ Wo2, float* __restrict__ bias2) {
  int idx = blockIdx.x * 256 + threadIdx.x;
  if (idx < C_) {
    float s = 0.f;
    for (int c = 0; c < C_; ++c) s += wout[idx * C_ + c] * bproj[c];
    bias2[idx] = s;
  }
  if (idx >= 4 * CC2) return;
  int which = idx / CC2;
  int rem = idx % CC2;
  int o = rem / C_, c = rem % C_;
  const float* A = (which == 0) ? wq : (which == 1) ? wk : (which == 2) ? wv : wout;
  const float* Bm = (which == 3) ? wproj : wsplit;
  float s = 0.f;
  for (int e = 0; e < C_; ++e) s += A[o * C_ + e] * Bm[e * C_ + c];
  if (which == 0) { Wq[rem] = s; WqT[c * C_ + o] = s; }
  else if (which == 1) Wk[rem] = s;
  else if (which == 2) Wv[rem] = s;
  else Wo2[rem] = s;
}

// ---------------- Gram: software-pipelined, double-buffered, no atomics ----------------
// grid (32 k-chunks, 8 batches), 384 threads (6 waves). Wave w owns G rows [32w,32w+32).
// ATOMIC=true is the small-workspace fallback (accumulates directly into G).
template <bool ATOMIC>
__global__ __launch_bounds__(384) void gram2_kernel(const float* __restrict__ xin,
                                                    float* __restrict__ dst) {
  const int b = blockIdx.y, ch = blockIdx.x;
  const int k0 = ch * 512;
  __shared__ unsigned short Xs[2][C_][72];         // double buffer, pitch 72 (2-way = free)
  const int tid = threadIdx.x;
  const int wv = tid >> 6;
  const int lane = tid & 63;
  const int ln = lane & 15, mq = lane >> 4;
  const int cbase = tid >> 4;                      // 0..23
  const int k4 = tid & 15;
  const float* xb = xin + (size_t)b * C_ * N_;

  f32x4 acc[2][12];
#pragma unroll
  for (int i = 0; i < 2; ++i)
#pragma unroll
    for (int j = 0; j < 12; ++j) acc[i][j] = (f32x4)0.0f;

  float4 ld[8];
  auto load_stage = [&](int kbase) {
#pragma unroll
    for (int j = 0; j < 8; ++j)
      ld[j] = *(const float4*)(xb + (size_t)(j * 24 + cbase) * N_ + kbase + k4 * 4);
  };
  auto write_stage = [&](int buf) {
#pragma unroll
    for (int j = 0; j < 8; ++j) {
      unsigned int lo = (unsigned)f2bf(ld[j].x) | ((unsigned)f2bf(ld[j].y) << 16);
      unsigned int hi = (unsigned)f2bf(ld[j].z) | ((unsigned)f2bf(ld[j].w) << 16);
      uint2 pk; pk.x = lo; pk.y = hi;
      *(uint2*)&Xs[buf][j * 24 + cbase][k4 * 4] = pk;    // ds_write_b64
    }
  };

  load_stage(k0);
  write_stage(0);
  __syncthreads();
  for (int s = 0; s < 8; ++s) {                    // 8 stages of 64 k
    if (s < 7) load_stage(k0 + (s + 1) * 64);      // prefetch overlaps MFMA below
    const int cb = s & 1;
#pragma unroll
    for (int ks = 0; ks < 2; ++ks) {
      const int kk = ks * 32 + mq * 8;
      u16x8 a0 = *(const u16x8*)&Xs[cb][32 * wv + ln][kk];
      u16x8 a1 = *(const u16x8*)&Xs[cb][32 * wv + 16 + ln][kk];
#pragma unroll
      for (int ct = 0; ct < 12; ++ct) {
        u16x8 bf = *(const u16x8*)&Xs[cb][ct * 16 + ln][kk];
        acc[0][ct] = mfma16(a0, bf, acc[0][ct]);
        acc[1][ct] = mfma16(a1, bf, acc[1][ct]);
      }
    }
    if (s < 7) {
      write_stage(cb ^ 1);   // safe: cb^1 was last read a full barrier ago
      __syncthreads();
    }
  }
  float* out = ATOMIC ? dst + (size_t)b * CC2
                      : dst + ((size_t)b * NCHUNK + ch) * CC2;
#pragma unroll
  for (int i = 0; i < 2; ++i)
#pragma unroll
    for (int ct = 0; ct < 12; ++ct)
#pragma unroll
      for (int r = 0; r < 4; ++r) {
        int row = 32 * wv + 16 * i + mq * 4 + r;
        int col = ct * 16 + ln;
        if (ATOMIC) atomicAdd(&out[row * C_ + col], acc[i][ct][r]);
        else out[row * C_ + col] = acc[i][ct][r];
      }
}

// reduce 32 partials -> G. grid (144, 8), 256 thr.
__global__ void gsum_kernel(const float* __restrict__ P, float* __restrict__ G) {
  const int j = blockIdx.x * 256 + threadIdx.x;
  const int b = blockIdx.y;
  const float* base = P + (size_t)b * NCHUNK * CC2 + j;
  float s0 = 0.f, s1 = 0.f, s2 = 0.f, s3 = 0.f;
#pragma unroll
  for (int ch = 0; ch < NCHUNK; ch += 4) {
    s0 += base[(size_t)ch * CC2];
    s1 += base[(size_t)(ch + 1) * CC2];
    s2 += base[(size_t)(ch + 2) * CC2];
    s3 += base[(size_t)(ch + 3) * CC2];
  }
  G[(size_t)b * CC2 + j] = (s0 + s1) + (s2 + s3);
}

// ---------------- middle ----------------
// Tk = Wk' G   (Tq is never needed in full — only its diagonal, see qn_kernel)
__global__ void tk_kernel(const float* __restrict__ Wk, const float* __restrict__ G,
                          float* __restrict__ Tk) {
  int idx = blockIdx.x * 256 + threadIdx.x;        // B*C*C
  if (idx >= B_ * CC2) return;
  int b = idx / CC2;
  int rc = idx % CC2;
  int d = rc / C_, cp = rc % C_;
  const float* Gb = G + (size_t)b * CC2;
  float s = 0.f;
  for (int c = 0; c < C_; ++c) s += Wk[d * C_ + c] * Gb[c * C_ + cp];
  Tk[idx] = s;
}

// qn[b,d] = sqrt(Wq[d]·G[b]·Wq[d]^T). block per (d,b), thread t = cp (coalesced G reads).
__global__ __launch_bounds__(192) void qn_kernel(const float* __restrict__ Wq,
                                                 const float* __restrict__ G,
                                                 float* __restrict__ qn) {
  const int b = blockIdx.y, d = blockIdx.x, t = threadIdx.x;
  const float* Gb = G + (size_t)b * CC2;
  float inner = 0.f;
  for (int c = 0; c < C_; ++c) inner += Wq[d * C_ + c] * Gb[c * C_ + t];
  float val = inner * Wq[d * C_ + t];
  __shared__ float red[256];
  red[t] = val;
  if (t < 64) red[192 + t] = 0.f;
  __syncthreads();
  for (int st = 128; st > 0; st >>= 1) {
    if (t < st) red[t] += red[t + st];
    __syncthreads();
  }
  if (t == 0) qn[b * C_ + d] = fmaxf(sqrtf(fmaxf(red[0], 0.f)), 1e-12f);
}

// block (b,cc): kn + logits row + softmax + Tv row (A·Wv fused, A never materialized)
__global__ __launch_bounds__(192) void attn_av_kernel(const float* __restrict__ Tk,
                                                      const float* __restrict__ WqT,
                                                      const float* __restrict__ Wk,
                                                      const float* __restrict__ Wv,
                                                      const float* __restrict__ qn,
                                                      float* __restrict__ Tv) {
  const int b = blockIdx.y, cc = blockIdx.x, t = threadIdx.x;
  __shared__ float tkrow[C_];
  __shared__ float arow[C_];
  __shared__ float red[256];
  tkrow[t] = Tk[((size_t)b * C_ + cc) * C_ + t];
  // kn = sqrt(dot(tkrow, Wk[cc,:]))  (each thread contributes its own element)
  red[t] = tkrow[t] * Wk[cc * C_ + t];
  if (t < 64) red[192 + t] = 0.f;
  __syncthreads();
  for (int st = 128; st > 0; st >>= 1) {
    if (t < st) red[t] += red[t + st];
    __syncthreads();
  }
  float knv = fmaxf(sqrtf(fmaxf(red[0], 0.f)), 1e-12f);
  __syncthreads();
  // logits: dd = t, coalesced via WqT
  float s = 0.f;
  for (int c = 0; c < C_; ++c) s += tkrow[c] * WqT[c * C_ + t];
  float lg = s / (knv * qn[b * C_ + t]);
  red[t] = lg;
  if (t < 64) red[192 + t] = -1e30f;
  __syncthreads();
  for (int st = 128; st > 0; st >>= 1) {
    if (t < st) red[t] = fmaxf(red[t], red[t + st]);
    __syncthreads();
  }
  float mx = red[0];
  __syncthreads();
  float e = expf(lg - mx);
  red[t] = e;
  if (t < 64) red[192 + t] = 0.f;
  __syncthreads();
  for (int st = 128; st > 0; st >>= 1) {
    if (t < st) red[t] += red[t + st];
    __syncthreads();
  }
  float a = e / red[0];
  arow[t] = a;
  __syncthreads();
  // Tv[cc, j] = sum_c A[cc,c] * Wv[c,j], j = t (coalesced Wv reads)
  float sv = 0.f;
  for (int c = 0; c < C_; ++c) sv += arow[c] * Wv[c * C_ + t];
  Tv[((size_t)b * C_ + cc) * C_ + t] = sv;
}

__global__ void m_kernel(const float* __restrict__ Wo2, const float* __restrict__ Tv,
                         float* __restrict__ Mout) {
  int idx = blockIdx.x * 256 + threadIdx.x;        // B*C*C
  if (idx >= B_ * CC2) return;
  int b = idx / CC2;
  int rc = idx % CC2;
  int i = rc / C_, j = rc % C_;
  float s = 0.f;
  for (int c = 0; c < C_; ++c) s += Wo2[i * C_ + c] * Tv[((size_t)b * C_ + c) * C_ + j];
  Mout[idx] = s;
}

// ---------------- final: out[b] = M[b] @ X[b] + bias2, bf16 MFMA ----------------
__global__ __launch_bounds__(384) void final_kernel(const float* __restrict__ xin,
                                                    const float* __restrict__ Mw,
                                                    const float* __restrict__ bias2,
                                                    float* __restrict__ out) {
  const int b = blockIdx.y;
  const int p0 = blockIdx.x * 128;
  __shared__ unsigned short Ts[128][200];          // pitch 200 (2-way conflicts only)
  const int tid = threadIdx.x;
  const int wv = tid >> 6;
  const int lane = tid & 63;
  const int ln = lane & 15, mq = lane >> 4;
  const float* Mb = Mw + (size_t)b * CC2;

  u16x8 afr[6][2];
  float bo[2][4];
#pragma unroll
  for (int i = 0; i < 2; ++i) {
    int row = 32 * wv + 16 * i + ln;
#pragma unroll
    for (int kc = 0; kc < 6; ++kc) {
      const float* src = Mb + row * C_ + kc * 32 + mq * 8;
      float4 u0 = *(const float4*)(src);
      float4 u1 = *(const float4*)(src + 4);
      u16x8 a;
      a[0] = f2bf(u0.x); a[1] = f2bf(u0.y); a[2] = f2bf(u0.z); a[3] = f2bf(u0.w);
      a[4] = f2bf(u1.x); a[5] = f2bf(u1.y); a[6] = f2bf(u1.z); a[7] = f2bf(u1.w);
      afr[kc][i] = a;
    }
#pragma unroll
    for (int r = 0; r < 4; ++r) bo[i][r] = bias2[32 * wv + 16 * i + mq * 4 + r];
  }

#pragma unroll
  for (int j = 0; j < 16; ++j) {
    int lin = j * 384 + tid;
    int c = lin >> 5, p4 = lin & 31;
    float4 v = *(const float4*)(xin + ((size_t)b * C_ + c) * N_ + p0 + p4 * 4);
    Ts[p4 * 4 + 0][c] = f2bf(v.x);
    Ts[p4 * 4 + 1][c] = f2bf(v.y);
    Ts[p4 * 4 + 2][c] = f2bf(v.z);
    Ts[p4 * 4 + 3][c] = f2bf(v.w);
  }
  __syncthreads();

#pragma unroll
  for (int pt = 0; pt < 8; ++pt) {
    f32x4 acc0 = (f32x4)0.0f, acc1 = (f32x4)0.0f;
#pragma unroll
    for (int kc = 0; kc < 6; ++kc) {
      u16x8 bf = *(const u16x8*)&Ts[pt * 16 + ln][kc * 32 + mq * 8];
      acc0 = mfma16(afr[kc][0], bf, acc0);
      acc1 = mfma16(afr[kc][1], bf, acc1);
    }
#pragma unroll
    for (int r = 0; r < 4; ++r) {
      int row0 = 32 * wv + mq * 4 + r;
      int row1 = row0 + 16;
      int p = p0 + pt * 16 + ln;
      out[((size_t)b * C_ + row0) * N_ + p] = acc0[r] + bo[0][r];
      out[((size_t)b * C_ + row1) * N_ + p] = acc1[r] + bo[1][r];
    }
  }
}

extern "C" void kernel_launch(void* const* d_in, const int* in_sizes, int n_in,
                              void* d_out, int out_size, void* d_ws, size_t ws_size,
                              hipStream_t stream) {
  const float* xin    = (const float*)d_in[0];
  const float* wsplit = (const float*)d_in[1];
  const float* wq     = (const float*)d_in[2];
  const float* wk     = (const float*)d_in[3];
  const float* wv     = (const float*)d_in[4];
  const float* wvv    = (const float*)d_in[4];
  (void)wvv;
  const float* wproj  = (const float*)d_in[5];
  const float* bproj  = (const float*)d_in[6];
  const float* wout   = (const float*)d_in[7];
  float* out = (float*)d_out;

  float* ws = (float*)d_ws;
  float* G     = ws;                         // B*CC2
  float* Wq    = G + (size_t)B_ * CC2;       // CC2
  float* WqT   = Wq + CC2;
  float* Wk    = WqT + CC2;
  float* Wv    = Wk + CC2;
  float* Wo2   = Wv + CC2;
  float* bias2 = Wo2 + CC2;                  // 256
  float* Tk    = bias2 + 256;                // B*CC2
  float* Tv    = Tk + (size_t)B_ * CC2;
  float* Mw    = Tv + (size_t)B_ * CC2;
  float* qn    = Mw + (size_t)B_ * CC2;      // B*C_
  float* P     = qn + 256 * B_;              // B*NCHUNK*CC2 (37.7 MB) if it fits

  size_t base_floats = (size_t)(P - ws);
  size_t need_bytes = (base_floats + (size_t)B_ * NCHUNK * CC2) * sizeof(float);
  bool use_partials = ws_size >= need_bytes;

  fold_kernel<<<(4 * CC2 + 255) / 256, 256, 0, stream>>>(
      wsplit, wq, wk, wv, wproj, bproj, wout, Wq, WqT, Wk, Wv, Wo2, bias2);
  if (use_partials) {
    gram2_kernel<false><<<dim3(NCHUNK, B_), 384, 0, stream>>>(xin, P);
    gsum_kernel<<<dim3(CC2 / 256, B_), 256, 0, stream>>>(P, G);
  } else {
    hipMemsetAsync(G, 0, (size_t)B_ * CC2 * sizeof(float), stream);
    gram2_kernel<true><<<dim3(NCHUNK, B_), 384, 0, stream>>>(xin, G);
  }
  tk_kernel<<<(B_ * CC2 + 255) / 256, 256, 0, stream>>>(Wk, G, Tk);
  qn_kernel<<<dim3(C_, B_), 192, 0, stream>>>(Wq, G, qn);
  attn_av_kernel<<<dim3(C_, B_), 192, 0, stream>>>(Tk, WqT, Wk, Wv, qn, Tv);
  m_kernel<<<(B_ * CC2 + 255) / 256, 256, 0, stream>>>(Wo2, Tv, Mw);
  final_kernel<<<dim3(N_ / 128, B_), 384, 0, stream>>>(xin, Mw, bias2, out);
}

// Round 3
// 323.662 us; speedup vs baseline: 1.2237x; 1.0341x over previous
//
#include <hip/hip_runtime.h>

// out[b] = M[b] @ X[b] + bias2, where (X = x_in[b] as [192,16384])
//   G[b]  = X X^T (Gram) ; Wq'=w_q@w_split etc.; Wo2=w_out@w_proj; bias2=w_out@b_proj
//   Tk = Wk' G ; qn[d]=sqrt(Wq'[d] G Wq'[d]^T) ; kn[cc]=sqrt(Tk[cc]·Wk'[cc])
//   A = softmax_rows(Tk Wq'^T / (kn ⊗ qn)) ; M = Wo2 (A Wv')
// Heavy phases (Gram, final GEMM) use bf16 MFMA 16x16x32 with fp32 accum.

static constexpr int B_ = 8;
static constexpr int C_ = 192;
static constexpr int N_ = 16384;
static constexpr int CC2 = C_ * C_;
static constexpr int NCHUNK = 32;

using u16x8 = __attribute__((ext_vector_type(8))) unsigned short;
using bf16x8 = __attribute__((ext_vector_type(8))) __bf16;
using f32x4 = __attribute__((ext_vector_type(4))) float;

__device__ __forceinline__ unsigned short f2bf(float f) {
  unsigned int u = __builtin_bit_cast(unsigned int, f);
  u += 0x7FFFu + ((u >> 16) & 1u);   // RNE
  return (unsigned short)(u >> 16);
}

__device__ __forceinline__ f32x4 mfma16(u16x8 a, u16x8 b, f32x4 c) {
  return __builtin_amdgcn_mfma_f32_16x16x32_bf16(
      __builtin_bit_cast(bf16x8, a), __builtin_bit_cast(bf16x8, b), c, 0, 0, 0);
}

// ---------------- fold weights ----------------
__global__ void fold_kernel(const float* __restrict__ wsplit, const float* __restrict__ wq,
                            const float* __restrict__ wk, const float* __restrict__ wv,
                            const float* __restrict__ wproj, const float* __restrict__ bproj,
                            const float* __restrict__ wout,
                            float* __restrict__ Wq, float* __restrict__ WqT,
                            float* __restrict__ Wk, float* __restrict__ Wv,
                            float* __restrict__ Wo2, float* __restrict__ bias2) {
  int idx = blockIdx.x * 256 + threadIdx.x;
  if (idx < C_) {
    float s = 0.f;
    for (int c = 0; c < C_; ++c) s += wout[idx * C_ + c] * bproj[c];
    bias2[idx] = s;
  }
  if (idx >= 4 * CC2) return;
  int which = idx / CC2;
  int rem = idx % CC2;
  int o = rem / C_, c = rem % C_;
  const float* A = (which == 0) ? wq : (which == 1) ? wk : (which == 2) ? wv : wout;
  const float* Bm = (which == 3) ? wproj : wsplit;
  float s = 0.f;
  for (int e = 0; e < C_; ++e) s += A[o * C_ + e] * Bm[e * C_ + c];
  if (which == 0) { Wq[rem] = s; WqT[c * C_ + o] = s; }
  else if (which == 1) Wk[rem] = s;
  else if (which == 2) Wv[rem] = s;
  else Wo2[rem] = s;
}

// ---------------- Gram: row-split x2 for 2 blocks/CU, double-buffered pipeline ----------
// grid (32 k-chunks, 2 row-halves, 8 batches) = 512 blocks, 384 thr (6 waves).
// Each block stages all 192 X-rows but computes only its 96 G-rows (wave: 16 rows).
template <bool ATOMIC>
__global__ __launch_bounds__(384) void gram3_kernel(const float* __restrict__ xin,
                                                    float* __restrict__ dst) {
  const int b = blockIdx.z, half = blockIdx.y, ch = blockIdx.x;
  const int k0 = ch * 512;
  __shared__ unsigned short Xs[2][C_][72];         // dbuf, pitch 72 (2-way = free)
  const int tid = threadIdx.x;
  const int wv = tid >> 6;                         // 0..5
  const int lane = tid & 63;
  const int ln = lane & 15, mq = lane >> 4;
  const int arow0 = half * 96 + wv * 16;           // this wave's 16 G-rows
  const int cbase = tid >> 4;                      // 0..23
  const int k4 = tid & 15;
  const float* xb = xin + (size_t)b * C_ * N_;

  f32x4 acc[12];
#pragma unroll
  for (int j = 0; j < 12; ++j) acc[j] = (f32x4)0.0f;

  float4 ld[8];
  auto load_stage = [&](int kbase) {
#pragma unroll
    for (int j = 0; j < 8; ++j)
      ld[j] = *(const float4*)(xb + (size_t)(j * 24 + cbase) * N_ + kbase + k4 * 4);
  };
  auto write_stage = [&](int buf) {
#pragma unroll
    for (int j = 0; j < 8; ++j) {
      unsigned int lo = (unsigned)f2bf(ld[j].x) | ((unsigned)f2bf(ld[j].y) << 16);
      unsigned int hi = (unsigned)f2bf(ld[j].z) | ((unsigned)f2bf(ld[j].w) << 16);
      uint2 pk; pk.x = lo; pk.y = hi;
      *(uint2*)&Xs[buf][j * 24 + cbase][k4 * 4] = pk;    // ds_write_b64
    }
  };

  load_stage(k0);
  write_stage(0);
  __syncthreads();
  for (int s = 0; s < 8; ++s) {                    // 8 stages of 64 k
    if (s < 7) load_stage(k0 + (s + 1) * 64);      // prefetch overlaps MFMA
    const int cb = s & 1;
#pragma unroll
    for (int ks = 0; ks < 2; ++ks) {
      const int kk = ks * 32 + mq * 8;
      u16x8 a0 = *(const u16x8*)&Xs[cb][arow0 + ln][kk];
#pragma unroll
      for (int ct = 0; ct < 12; ++ct) {
        u16x8 bf = *(const u16x8*)&Xs[cb][ct * 16 + ln][kk];
        acc[ct] = mfma16(a0, bf, acc[ct]);
      }
    }
    if (s < 7) {
      write_stage(cb ^ 1);   // safe: cb^1 last read a full barrier ago
      __syncthreads();
    }
  }
  float* out = ATOMIC ? dst + (size_t)b * CC2
                      : dst + ((size_t)b * NCHUNK + ch) * CC2;
#pragma unroll
  for (int ct = 0; ct < 12; ++ct)
#pragma unroll
    for (int r = 0; r < 4; ++r) {
      int row = arow0 + mq * 4 + r;
      int col = ct * 16 + ln;
      if (ATOMIC) atomicAdd(&out[row * C_ + col], acc[ct][r]);
      else out[row * C_ + col] = acc[ct][r];
    }
}

// reduce 32 partials -> G. float4. grid (CC2/1024, 8), 256 thr.
__global__ void gsum_kernel(const float* __restrict__ P, float* __restrict__ G) {
  const int j = (blockIdx.x * 256 + threadIdx.x) * 4;
  const int b = blockIdx.y;
  const float* base = P + (size_t)b * NCHUNK * CC2 + j;
  float4 s = {0.f, 0.f, 0.f, 0.f};
#pragma unroll
  for (int ch = 0; ch < NCHUNK; ++ch) {
    float4 v = *(const float4*)(base + (size_t)ch * CC2);
    s.x += v.x; s.y += v.y; s.z += v.z; s.w += v.w;
  }
  *(float4*)(G + (size_t)b * CC2 + j) = s;
}

// ---------------- middle ----------------
// block (b,d): Tk row d = Wk[d]·G  AND  qn[b,d] = sqrt(Wq[d]·G·Wq[d]^T). Shares G reads.
__global__ __launch_bounds__(192) void tkqn_kernel(const float* __restrict__ Wk,
                                                   const float* __restrict__ Wq,
                                                   const float* __restrict__ G,
                                                   float* __restrict__ Tk,
                                                   float* __restrict__ qn) {
  const int b = blockIdx.y, d = blockIdx.x, t = threadIdx.x;
  const float* Gb = G + (size_t)b * CC2;
  float sk = 0.f, sq = 0.f;
  for (int c = 0; c < C_; ++c) {
    float g = Gb[c * C_ + t];
    sk += Wk[d * C_ + c] * g;
    sq += Wq[d * C_ + c] * g;
  }
  Tk[((size_t)b * C_ + d) * C_ + t] = sk;
  float val = sq * Wq[d * C_ + t];
  __shared__ float red[256];
  red[t] = val;
  if (t < 64) red[192 + t] = 0.f;
  __syncthreads();
  for (int st = 128; st > 0; st >>= 1) {
    if (t < st) red[t] += red[t + st];
    __syncthreads();
  }
  if (t == 0) qn[b * C_ + d] = fmaxf(sqrtf(fmaxf(red[0], 0.f)), 1e-12f);
}

// block (b,cc): kn + logits row + softmax + Tv row (A never materialized)
__global__ __launch_bounds__(192) void attn_av_kernel(const float* __restrict__ Tk,
                                                      const float* __restrict__ WqT,
                                                      const float* __restrict__ Wk,
                                                      const float* __restrict__ Wv,
                                                      const float* __restrict__ qn,
                                                      float* __restrict__ Tv) {
  const int b = blockIdx.y, cc = blockIdx.x, t = threadIdx.x;
  __shared__ float tkrow[C_];
  __shared__ float arow[C_];
  __shared__ float red[256];
  tkrow[t] = Tk[((size_t)b * C_ + cc) * C_ + t];
  red[t] = tkrow[t] * Wk[cc * C_ + t];
  if (t < 64) red[192 + t] = 0.f;
  __syncthreads();
  for (int st = 128; st > 0; st >>= 1) {
    if (t < st) red[t] += red[t + st];
    __syncthreads();
  }
  float knv = fmaxf(sqrtf(fmaxf(red[0], 0.f)), 1e-12f);
  __syncthreads();
  float s = 0.f;
  for (int c = 0; c < C_; ++c) s += tkrow[c] * WqT[c * C_ + t];
  float lg = s / (knv * qn[b * C_ + t]);
  red[t] = lg;
  if (t < 64) red[192 + t] = -1e30f;
  __syncthreads();
  for (int st = 128; st > 0; st >>= 1) {
    if (t < st) red[t] = fmaxf(red[t], red[t + st]);
    __syncthreads();
  }
  float mx = red[0];
  __syncthreads();
  float e = expf(lg - mx);
  red[t] = e;
  if (t < 64) red[192 + t] = 0.f;
  __syncthreads();
  for (int st = 128; st > 0; st >>= 1) {
    if (t < st) red[t] += red[t + st];
    __syncthreads();
  }
  float a = e / red[0];
  arow[t] = a;
  __syncthreads();
  float sv = 0.f;
  for (int c = 0; c < C_; ++c) sv += arow[c] * Wv[c * C_ + t];
  Tv[((size_t)b * C_ + cc) * C_ + t] = sv;
}

__global__ void m_kernel(const float* __restrict__ Wo2, const float* __restrict__ Tv,
                         float* __restrict__ Mout) {
  int idx = blockIdx.x * 256 + threadIdx.x;        // B*C*C
  if (idx >= B_ * CC2) return;
  int b = idx / CC2;
  int rc = idx % CC2;
  int i = rc / C_, j = rc % C_;
  float s = 0.f;
  for (int c = 0; c < C_; ++c) s += Wo2[i * C_ + c] * Tv[((size_t)b * C_ + c) * C_ + j];
  Mout[idx] = s;
}

// ---------------- final: out[b] = M[b] @ X[b] + bias2, bf16 MFMA ----------------
// XOR-swizzled LDS: X[c][p] stored at Ts[p*192 + 8*((c>>3)^(p&7)) + (c&7)].
// Frag reads (key = ln&7) spread over all 8 bank-groups -> 2-way (free).
// Writes rotate the float4 element by (p4>>1) so the per-inst key takes 8 values.
__global__ __launch_bounds__(384) void final2_kernel(const float* __restrict__ xin,
                                                     const float* __restrict__ Mw,
                                                     const float* __restrict__ bias2,
                                                     float* __restrict__ out) {
  const int b = blockIdx.y;
  const int p0 = blockIdx.x * 128;
  __shared__ unsigned short Ts[128 * 192];         // 48 KB, no pad (swizzled)
  const int tid = threadIdx.x;
  const int wv = tid >> 6;
  const int lane = tid & 63;
  const int ln = lane & 15, mq = lane >> 4;
  const float* Mb = Mw + (size_t)b * CC2;

  u16x8 afr[6][2];
  float bo[2][4];
#pragma unroll
  for (int i = 0; i < 2; ++i) {
    int row = 32 * wv + 16 * i + ln;
#pragma unroll
    for (int kc = 0; kc < 6; ++kc) {
      const float* src = Mb + row * C_ + kc * 32 + mq * 8;
      float4 u0 = *(const float4*)(src);
      float4 u1 = *(const float4*)(src + 4);
      u16x8 a;
      a[0] = f2bf(u0.x); a[1] = f2bf(u0.y); a[2] = f2bf(u0.z); a[3] = f2bf(u0.w);
      a[4] = f2bf(u1.x); a[5] = f2bf(u1.y); a[6] = f2bf(u1.z); a[7] = f2bf(u1.w);
      afr[kc][i] = a;
    }
#pragma unroll
    for (int r = 0; r < 4; ++r) bo[i][r] = bias2[32 * wv + 16 * i + mq * 4 + r];
  }

#pragma unroll
  for (int j = 0; j < 16; ++j) {
    int lin = j * 384 + tid;
    int c = lin >> 5, p4 = lin & 31;
    float4 v = *(const float4*)(xin + ((size_t)b * C_ + c) * N_ + p0 + p4 * 4);
#pragma unroll
    for (int jj = 0; jj < 4; ++jj) {
      int e = (jj + (p4 >> 1)) & 3;                // rotation: 8 distinct p&7 keys per inst
      float val = (e == 0) ? v.x : (e == 1) ? v.y : (e == 2) ? v.z : v.w;
      int p = p4 * 4 + e;
      int idx = p * 192 + ((((c >> 3) ^ (p & 7)) << 3) | (c & 7));
      Ts[idx] = f2bf(val);
    }
  }
  __syncthreads();

#pragma unroll
  for (int pt = 0; pt < 8; ++pt) {
    const int p = pt * 16 + ln;
    f32x4 acc0 = (f32x4)0.0f, acc1 = (f32x4)0.0f;
#pragma unroll
    for (int kc = 0; kc < 6; ++kc) {
      u16x8 bf = *(const u16x8*)&Ts[p * 192 + (((kc * 4 + mq) ^ (p & 7)) << 3)];
      acc0 = mfma16(afr[kc][0], bf, acc0);
      acc1 = mfma16(afr[kc][1], bf, acc1);
    }
#pragma unroll
    for (int r = 0; r < 4; ++r) {
      int row0 = 32 * wv + mq * 4 + r;
      int row1 = row0 + 16;
      int pp = p0 + pt * 16 + ln;
      out[((size_t)b * C_ + row0) * N_ + pp] = acc0[r] + bo[0][r];
      out[((size_t)b * C_ + row1) * N_ + pp] = acc1[r] + bo[1][r];
    }
  }
}

extern "C" void kernel_launch(void* const* d_in, const int* in_sizes, int n_in,
                              void* d_out, int out_size, void* d_ws, size_t ws_size,
                              hipStream_t stream) {
  const float* xin    = (const float*)d_in[0];
  const float* wsplit = (const float*)d_in[1];
  const float* wq     = (const float*)d_in[2];
  const float* wk     = (const float*)d_in[3];
  const float* wv     = (const float*)d_in[4];
  const float* wproj  = (const float*)d_in[5];
  const float* bproj  = (const float*)d_in[6];
  const float* wout   = (const float*)d_in[7];
  float* out = (float*)d_out;

  float* ws = (float*)d_ws;
  float* G     = ws;                         // B*CC2
  float* Wq    = G + (size_t)B_ * CC2;       // CC2
  float* WqT   = Wq + CC2;
  float* Wk    = WqT + CC2;
  float* Wv    = Wk + CC2;
  float* Wo2   = Wv + CC2;
  float* bias2 = Wo2 + CC2;                  // 256
  float* Tk    = bias2 + 256;                // B*CC2
  float* Tv    = Tk + (size_t)B_ * CC2;
  float* Mw    = Tv + (size_t)B_ * CC2;
  float* qn    = Mw + (size_t)B_ * CC2;      // B*C_ (pad 256)
  float* P     = qn + 256 * B_;              // B*NCHUNK*CC2 (37.7 MB) if it fits

  size_t base_floats = (size_t)(P - ws);
  size_t need_bytes = (base_floats + (size_t)B_ * NCHUNK * CC2) * sizeof(float);
  bool use_partials = ws_size >= need_bytes;

  fold_kernel<<<(4 * CC2 + 255) / 256, 256, 0, stream>>>(
      wsplit, wq, wk, wv, wproj, bproj, wout, Wq, WqT, Wk, Wv, Wo2, bias2);
  if (use_partials) {
    gram3_kernel<false><<<dim3(NCHUNK, 2, B_), 384, 0, stream>>>(xin, P);
    gsum_kernel<<<dim3(CC2 / 1024, B_), 256, 0, stream>>>(P, G);
  } else {
    hipMemsetAsync(G, 0, (size_t)B_ * CC2 * sizeof(float), stream);
    gram3_kernel<true><<<dim3(NCHUNK, 2, B_), 384, 0, stream>>>(xin, G);
  }
  tkqn_kernel<<<dim3(C_, B_), 192, 0, stream>>>(Wk, Wq, G, Tk, qn);
  attn_av_kernel<<<dim3(C_, B_), 192, 0, stream>>>(Tk, WqT, Wk, Wv, qn, Tv);
  m_kernel<<<(B_ * CC2 + 255) / 256, 256, 0, stream>>>(Wo2, Tv, Mw);
  final2_kernel<<<dim3(N_ / 128, B_), 384, 0, stream>>>(xin, Mw, bias2, out);
}